// Round 3
// baseline (396.589 us; speedup 1.0000x reference)
//
#include <hip/hip_runtime.h>

#define F_IN 128
#define HID 16
#define HEADS 12
#define HF (HEADS*HID)   // 192
#define OUT_C 32

// ---------------- edge_index dtype probe + conversion ----------------
// Reference declares edge_index as int64; harness contract says int32. Detect
// on-device: sample odd int32 words of the first E elements. int64 data (all
// values < 2^31) has ALL high words == 0; int32 data has random node ids there.
__global__ void k_detect(const int* __restrict__ ei, int E, int* __restrict__ flag) {
    int t = threadIdx.x;                     // single block of 256
    long long half = (long long)E;           // sample k in [0, E)
    int acc = 0;
    #pragma unroll
    for (int i = 0; i < 8; i++) {
        long long k = ((long long)(t + i * 256) * half) / 2048;
        acc |= ei[2 * k + 1];
    }
    if (acc) atomicOr(&flag[1], 1);          // flag[1]!=0  =>  data is int32
}

// Normalize to int32 src/dst; fused in-degree count (replaces k_count).
__global__ void k_convert(const void* __restrict__ ei, int E, const int* __restrict__ flag,
                          int* __restrict__ src32, int* __restrict__ dst32,
                          int* __restrict__ count) {
    int e = blockIdx.x * blockDim.x + threadIdx.x;
    if (e >= E) return;
    int s, d;
    if (flag[1] == 0) {                      // int64 layout
        const long long* p = (const long long*)ei;
        s = (int)p[e];
        d = (int)p[(size_t)E + e];
    } else {                                 // int32 layout
        const int* p = (const int*)ei;
        s = p[e];
        d = p[(size_t)E + e];
    }
    src32[e] = s;
    dst32[e] = d;
    atomicAdd(&count[d], 1);
}

// ---------------- CSR build ----------------

// single block, 1024 threads: exclusive prefix sum of count -> rowstart, plus dinv
__global__ void k_scan(const int* __restrict__ count, int* __restrict__ rowstart,
                       float* __restrict__ dinv, int n) {
    __shared__ int part[1024];
    int t = threadIdx.x;
    int chunk = (n + 1023) >> 10;
    int beg = t * chunk;
    int end = beg + chunk; if (end > n) end = n;
    int s = 0;
    for (int i = beg; i < end; i++) s += count[i];
    part[t] = s;
    __syncthreads();
    for (int off = 1; off < 1024; off <<= 1) {
        int v = (t >= off) ? part[t - off] : 0;
        __syncthreads();
        part[t] += v;
        __syncthreads();
    }
    int run = (t == 0) ? 0 : part[t - 1];
    for (int i = beg; i < end; i++) {
        rowstart[i] = run;
        int c = count[i];
        run += c;
        dinv[i] = rsqrtf((float)(c + 1));   // +1 self loop; deg>=1 always
    }
    if (t == 1023) rowstart[n] = run;
}

__global__ void k_fill(const int* __restrict__ srcA, const int* __restrict__ dstA, int E,
                       const int* __restrict__ rowstart, int* __restrict__ cursor,
                       int* __restrict__ csr) {
    int e = blockIdx.x * blockDim.x + threadIdx.x;
    if (e < E) {
        int d = dstA[e];
        int p = atomicAdd(&cursor[d], 1);
        csr[rowstart[d] + p] = srcA[e];
    }
}

// ---------------- GEMM kernels (small K, fp32 VALU) ----------------

// h1 = x(N,128) @ W1(128,16) ; block=256 handles 16 nodes x 16 cols
__global__ void k_gemm1(const float* __restrict__ x, const float* __restrict__ W,
                        float* __restrict__ h, int n) {
    __shared__ float sW[F_IN * HID];       // 8KB
    __shared__ float sX[16][F_IN + 1];     // padded vs bank conflicts
    int t = threadIdx.x;
    for (int i = t; i < F_IN * HID; i += 256) sW[i] = W[i];
    int node0 = blockIdx.x * 16;
    for (int i = t; i < 16 * F_IN; i += 256) {
        int r = i >> 7, c = i & 127;
        int node = node0 + r;
        sX[r][c] = (node < n) ? x[node * F_IN + c] : 0.f;
    }
    __syncthreads();
    int ln = t >> 4, c = t & 15;
    float acc = 0.f;
    #pragma unroll 8
    for (int k = 0; k < F_IN; k++) acc += sX[ln][k] * sW[k * HID + c];
    int node = node0 + ln;
    if (node < n) h[node * HID + c] = acc;
}

// hg = x1(N,16) @ Wg(16,192), fused attention dots a_s/a_d. block=384 = 2 nodes x 192
__global__ void k_gemm_gat(const float* __restrict__ x1, const float* __restrict__ Wg,
                           const float* __restrict__ att_s, const float* __restrict__ att_d,
                           float* __restrict__ hg, float* __restrict__ a_s,
                           float* __restrict__ a_d, int n) {
    __shared__ float sW[HID * HF];   // 12KB
    __shared__ float sX[2][HID];
    int t = threadIdx.x;
    for (int i = t; i < HID * HF; i += 384) sW[i] = Wg[i];
    int node0 = blockIdx.x * 2;
    if (t < 2 * HID) {
        int r = t >> 4, c = t & 15;
        int node = node0 + r;
        sX[r][c] = (node < n) ? x1[node * HID + c] : 0.f;
    }
    __syncthreads();
    int ln = t / HF, c = t % HF;
    int node = node0 + ln;
    float acc = 0.f;
    #pragma unroll
    for (int k = 0; k < HID; k++) acc += sX[ln][k] * sW[k * HF + c];
    if (node < n) hg[(size_t)node * HF + c] = acc;
    // attention dots: 16-lane group reduce (groups aligned: 64 | multiples of 16)
    int hh = c >> 4, ci = c & 15;
    float vs = acc * att_s[hh * HID + ci];
    float vd = acc * att_d[hh * HID + ci];
    #pragma unroll
    for (int msk = 8; msk >= 1; msk >>= 1) {
        vs += __shfl_xor(vs, msk);
        vd += __shfl_xor(vd, msk);
    }
    if (ci == 0 && node < n) {
        a_s[node * HEADS + hh] = vs;
        a_d[node * HEADS + hh] = vd;
    }
}

// h2 = x2(N,192) @ W2(192,16) ; block=256 = 16 nodes x 16 cols
__global__ void k_gemm2(const float* __restrict__ x2, const float* __restrict__ W,
                        float* __restrict__ h, int n) {
    __shared__ float sW[HF * HID];       // 12KB
    __shared__ float sX[16][HF + 1];     // ~12.4KB
    int t = threadIdx.x;
    for (int i = t; i < HF * HID; i += 256) sW[i] = W[i];
    int node0 = blockIdx.x * 16;
    for (int i = t; i < 16 * HF; i += 256) {
        int r = i / HF, c = i % HF;
        int node = node0 + r;
        sX[r][c] = (node < n) ? x2[(size_t)node * HF + c] : 0.f;
    }
    __syncthreads();
    int ln = t >> 4, c = t & 15;
    float acc = 0.f;
    #pragma unroll 8
    for (int k = 0; k < HF; k++) acc += sX[ln][k] * sW[k * HID + c];
    int node = node0 + ln;
    if (node < n) h[node * HID + c] = acc;
}

// h3 = x3(N,16) @ W3(16,16)
__global__ void k_gemm3(const float* __restrict__ x3, const float* __restrict__ W,
                        float* __restrict__ h, int n) {
    __shared__ float sW[HID * HID];
    __shared__ float sX[16][HID + 1];
    int t = threadIdx.x;
    sW[t] = W[t];   // block is exactly 256
    int node0 = blockIdx.x * 16;
    int r = t >> 4, cc = t & 15;
    int nd = node0 + r;
    sX[r][cc] = (nd < n) ? x3[nd * HID + cc] : 0.f;
    __syncthreads();
    float acc = 0.f;
    #pragma unroll
    for (int k = 0; k < HID; k++) acc += sX[r][k] * sW[k * HID + cc];
    if (nd < n) h[nd * HID + cc] = acc;
}

// ---------------- Aggregation kernels (CSR, no atomics) ----------------

// GCN aggregate: out = relu(dinv[n]*(sum_src h[src]*dinv[src] + h[n]*dinv[n]) + bias) [+resid]
__global__ void k_gcn_agg(const float* __restrict__ h, const int* __restrict__ rowstart,
                          const int* __restrict__ csr, const float* __restrict__ dinv,
                          const float* __restrict__ bias, const float* __restrict__ resid,
                          float* __restrict__ out, int n) {
    int t = blockIdx.x * blockDim.x + threadIdx.x;
    int node = t >> 4, c = t & 15;
    if (node >= n) return;
    float dn = dinv[node];
    float acc = h[node * HID + c] * dn;          // self loop (x dn again below)
    int base = rowstart[node], endr = rowstart[node + 1];
    for (int j = base; j < endr; j++) {
        int s = csr[j];
        acc += h[s * HID + c] * dinv[s];
    }
    float v = fmaxf(acc * dn + bias[c], 0.f);
    if (resid) v += resid[node * HID + c];
    out[node * HID + c] = v;
}

// GAT aggregate: one wave per node; online softmax per head in registers.
// Fuses +bg and elu -> writes x2 directly.
__global__ void k_gat_agg(const float* __restrict__ hg, const float* __restrict__ a_s,
                          const float* __restrict__ a_d, const int* __restrict__ rowstart,
                          const int* __restrict__ csr, const float* __restrict__ bg,
                          float* __restrict__ x2, int n) {
    int wid = (blockIdx.x * blockDim.x + threadIdx.x) >> 6;
    int lane = threadIdx.x & 63;
    int node = wid;
    if (node >= n) return;
    int base = rowstart[node], deg = rowstart[node + 1] - base;

    // phase A: every lane runs a head (lane%12); lanes 0..11 are the shfl sources
    int hA = lane % 12;
    float adA = a_d[node * HEADS + hA];
    float e0 = a_s[node * HEADS + hA] + adA;     // self loop
    e0 = (e0 > 0.f) ? e0 : 0.2f * e0;
    float m = e0, s = 1.f;
    for (int j = 0; j < deg; j++) {
        int src = csr[base + j];
        float e = a_s[src * HEADS + hA] + adA;
        e = (e > 0.f) ? e : 0.2f * e;
        float nm = fmaxf(m, e);
        s = s * __expf(m - nm) + __expf(e - nm);
        m = nm;
    }

    // distribute per-head (m, 1/s, a_d) to the lanes that need them
    float mh[3], ish[3], adh[3], acc[3];
    #pragma unroll
    for (int it = 0; it < 3; it++) {
        int c = lane + 64 * it;
        int hh = c >> 4;                          // 0..11
        mh[it]  = __shfl(m, hh);
        ish[it] = 1.f / __shfl(s, hh);
        adh[it] = __shfl(adA, hh);
        // self-loop contribution
        float e = a_s[node * HEADS + hh] + adh[it];
        e = (e > 0.f) ? e : 0.2f * e;
        acc[it] = __expf(e - mh[it]) * ish[it] * hg[(size_t)node * HF + c];
    }
    for (int j = 0; j < deg; j++) {
        int src = csr[base + j];
        #pragma unroll
        for (int it = 0; it < 3; it++) {
            int c = lane + 64 * it;
            int hh = c >> 4;
            float e = a_s[src * HEADS + hh] + adh[it];
            e = (e > 0.f) ? e : 0.2f * e;
            float alpha = __expf(e - mh[it]) * ish[it];
            acc[it] += alpha * hg[(size_t)src * HF + c];
        }
    }
    #pragma unroll
    for (int it = 0; it < 3; it++) {
        int c = lane + 64 * it;
        float v = acc[it] + bg[c];
        v = (v > 0.f) ? v : (__expf(v) - 1.f);    // elu
        x2[(size_t)node * HF + c] = v;
    }
}

// ---------------- Final reduce + linear ----------------

__global__ void k_mean(const float* __restrict__ x4, float* __restrict__ red, int n) {
    __shared__ float sd[16][17];
    int t = threadIdx.x;
    int ln = t >> 4, c = t & 15;
    float acc = 0.f;
    for (int node = blockIdx.x * 16 + ln; node < n; node += gridDim.x * 16)
        acc += x4[node * HID + c];
    sd[ln][c] = acc;
    __syncthreads();
    for (int off = 8; off >= 1; off >>= 1) {
        if (ln < off) sd[ln][c] += sd[ln + off][c];
        __syncthreads();
    }
    if (ln == 0) atomicAdd(&red[c], sd[0][c]);
}

__global__ void k_final(const float* __restrict__ red, const float* __restrict__ Wlin,
                        const float* __restrict__ blin, float* __restrict__ out, float invN) {
    int o = threadIdx.x;
    if (o >= OUT_C) return;
    float acc = blin[o];
    #pragma unroll
    for (int c = 0; c < HID; c++) acc += (red[c] * invN) * Wlin[c * OUT_C + o];
    out[o] = acc;
}

// ---------------- launch ----------------

extern "C" void kernel_launch(void* const* d_in, const int* in_sizes, int n_in,
                              void* d_out, int out_size, void* d_ws, size_t ws_size,
                              hipStream_t stream) {
    const float* x     = (const float*)d_in[0];
    const void*  ei    = d_in[1];
    const float* W1    = (const float*)d_in[2];
    const float* b1    = (const float*)d_in[3];
    const float* Wg    = (const float*)d_in[4];
    const float* att_s = (const float*)d_in[5];
    const float* att_d = (const float*)d_in[6];
    const float* bg    = (const float*)d_in[7];
    const float* W2    = (const float*)d_in[8];
    const float* b2    = (const float*)d_in[9];
    const float* W3    = (const float*)d_in[10];
    const float* b3    = (const float*)d_in[11];
    const float* Wlin  = (const float*)d_in[12];
    const float* blin  = (const float*)d_in[13];
    float* out = (float*)d_out;

    int N = in_sizes[0] / F_IN;
    int E = in_sizes[1] / 2;

    char* w = (char*)d_ws;
    size_t off = 0;
    auto alloc = [&](size_t bytes) -> void* {
        void* p = w + off;
        off += (bytes + 255) & ~(size_t)255;
        return p;
    };
    int*   flag     = (int*)alloc(256);
    int*   src32    = (int*)alloc((size_t)E * 4);
    int*   dst32    = (int*)alloc((size_t)E * 4);
    int*   count    = (int*)alloc((size_t)N * 4);
    int*   rowstart = (int*)alloc((size_t)(N + 1) * 4);
    int*   cursor   = (int*)alloc((size_t)N * 4);
    int*   csr      = (int*)alloc((size_t)E * 4);
    float* dinv     = (float*)alloc((size_t)N * 4);
    float* h1       = (float*)alloc((size_t)N * HID * 4);
    float* x1       = (float*)alloc((size_t)N * HID * 4);
    float* hg       = (float*)alloc((size_t)N * HF * 4);
    float* a_s      = (float*)alloc((size_t)N * HEADS * 4);
    float* a_d      = (float*)alloc((size_t)N * HEADS * 4);
    float* x2       = (float*)alloc((size_t)N * HF * 4);
    float* h2       = (float*)alloc((size_t)N * HID * 4);
    float* x3       = (float*)alloc((size_t)N * HID * 4);
    float* h3       = (float*)alloc((size_t)N * HID * 4);
    float* x4       = (float*)alloc((size_t)N * HID * 4);
    float* red      = (float*)alloc(64);
    if (off > ws_size) return;   // ws too small: leave output poisoned (diagnosable)

    hipMemsetAsync(flag, 0, 256, stream);
    hipMemsetAsync(count, 0, (size_t)N * 4, stream);
    hipMemsetAsync(cursor, 0, (size_t)N * 4, stream);
    hipMemsetAsync(red, 0, 64, stream);

    int eb = (E + 255) / 256;
    int nb16 = (N + 15) / 16;

    k_detect<<<1, 256, 0, stream>>>((const int*)ei, E, flag);
    k_convert<<<eb, 256, 0, stream>>>(ei, E, flag, src32, dst32, count);
    k_scan<<<1, 1024, 0, stream>>>(count, rowstart, dinv, N);
    k_fill<<<eb, 256, 0, stream>>>(src32, dst32, E, rowstart, cursor, csr);

    k_gemm1<<<nb16, 256, 0, stream>>>(x, W1, h1, N);
    k_gcn_agg<<<nb16, 256, 0, stream>>>(h1, rowstart, csr, dinv, b1, nullptr, x1, N);

    k_gemm_gat<<<(N + 1) / 2, 384, 0, stream>>>(x1, Wg, att_s, att_d, hg, a_s, a_d, N);
    k_gat_agg<<<(N + 3) / 4, 256, 0, stream>>>(hg, a_s, a_d, rowstart, csr, bg, x2, N);

    k_gemm2<<<nb16, 256, 0, stream>>>(x2, W2, h2, N);
    k_gcn_agg<<<nb16, 256, 0, stream>>>(h2, rowstart, csr, dinv, b2, nullptr, x3, N);

    k_gemm3<<<nb16, 256, 0, stream>>>(x3, W3, h3, N);
    k_gcn_agg<<<nb16, 256, 0, stream>>>(h3, rowstart, csr, dinv, b3, x3, x4, N);

    k_mean<<<64, 256, 0, stream>>>(x4, red, N);
    k_final<<<1, 64, 0, stream>>>(red, Wlin, blin, out, 1.0f / (float)N);
}

// Round 6
// 351.223 us; speedup vs baseline: 1.1292x; 1.1292x over previous
//
#include <hip/hip_runtime.h>

#define F_IN 128
#define HID 16
#define HEADS 12
#define HF (HEADS*HID)   // 192
#define OUT_C 32

// ---------------- edge_index dtype probe + conversion ----------------
__global__ void k_detect(const int* __restrict__ ei, int E, int* __restrict__ flag) {
    int t = threadIdx.x;                     // single block of 256
    long long half = (long long)E;
    int acc = 0;
    #pragma unroll
    for (int i = 0; i < 8; i++) {
        long long k = ((long long)(t + i * 256) * half) / 2048;
        acc |= ei[2 * k + 1];
    }
    if (acc) atomicOr(&flag[1], 1);          // flag[1]!=0 => data is int32
}

__global__ void k_convert(const void* __restrict__ ei, int E, const int* __restrict__ flag,
                          int* __restrict__ src32, int* __restrict__ dst32,
                          int* __restrict__ count) {
    int e = blockIdx.x * blockDim.x + threadIdx.x;
    if (e >= E) return;
    int s, d;
    if (flag[1] == 0) {                      // int64 layout
        const long long* p = (const long long*)ei;
        s = (int)p[e];
        d = (int)p[(size_t)E + e];
    } else {                                 // int32 layout
        const int* p = (const int*)ei;
        s = p[e];
        d = p[(size_t)E + e];
    }
    src32[e] = s;
    dst32[e] = d;
    atomicAdd(&count[d], 1);
}

// ---------------- CSR build ----------------

__global__ void k_scan(const int* __restrict__ count, int* __restrict__ rowstart,
                       float* __restrict__ dinv, int n) {
    __shared__ int part[1024];
    int t = threadIdx.x;
    int chunk = (n + 1023) >> 10;
    int beg = t * chunk;
    int end = beg + chunk; if (end > n) end = n;
    int s = 0;
    for (int i = beg; i < end; i++) s += count[i];
    part[t] = s;
    __syncthreads();
    for (int off = 1; off < 1024; off <<= 1) {
        int v = (t >= off) ? part[t - off] : 0;
        __syncthreads();
        part[t] += v;
        __syncthreads();
    }
    int run = (t == 0) ? 0 : part[t - 1];
    for (int i = beg; i < end; i++) {
        rowstart[i] = run;
        int c = count[i];
        run += c;
        dinv[i] = rsqrtf((float)(c + 1));   // +1 self loop
    }
    if (t == 1023) rowstart[n] = run;
}

__global__ void k_fill(const int* __restrict__ srcA, const int* __restrict__ dstA, int E,
                       const int* __restrict__ rowstart, int* __restrict__ cursor,
                       int* __restrict__ csr) {
    int e = blockIdx.x * blockDim.x + threadIdx.x;
    if (e < E) {
        int d = dstA[e];
        int p = atomicAdd(&cursor[d], 1);
        csr[rowstart[d] + p] = srcA[e];
    }
}

// ---------------- GEMM kernels ----------------

// h1 = x(N,128) @ W1(128,16)
__global__ void k_gemm1(const float* __restrict__ x, const float* __restrict__ W,
                        float* __restrict__ h, int n) {
    __shared__ float sW[F_IN * HID];
    __shared__ float sX[16][F_IN + 1];
    int t = threadIdx.x;
    for (int i = t; i < F_IN * HID; i += 256) sW[i] = W[i];
    int node0 = blockIdx.x * 16;
    for (int i = t; i < 16 * F_IN; i += 256) {
        int r = i >> 7, c = i & 127;
        int node = node0 + r;
        sX[r][c] = (node < n) ? x[node * F_IN + c] : 0.f;
    }
    __syncthreads();
    int ln = t >> 4, c = t & 15;
    float acc = 0.f;
    #pragma unroll 8
    for (int k = 0; k < F_IN; k++) acc += sX[ln][k] * sW[k * HID + c];
    int node = node0 + ln;
    if (node < n) h[node * HID + c] = acc;
}

// hg = x1(N,16) @ Wg(16,192) + fused attention dots.
// Persistent blocks: weight column lives in registers; x row broadcast by shfl.
// No LDS, no __syncthreads.
__global__ void k_gemm_gat(const float* __restrict__ x1, const float* __restrict__ Wg,
                           const float* __restrict__ att_s, const float* __restrict__ att_d,
                           float* __restrict__ hg, float* __restrict__ a_s,
                           float* __restrict__ a_d, int n) {
    int c = threadIdx.x;          // 0..191 output column
    int lane = c & 63;
    int hh = c >> 4, ci = c & 15;
    float ats = att_s[c];         // (HEADS,HID) row-major == flat c
    float atd = att_d[c];
    float wcol[HID];
    #pragma unroll
    for (int k = 0; k < HID; k++) wcol[k] = Wg[k * HF + c];   // coalesced per k
    for (int node = blockIdx.x; node < n; node += gridDim.x) {
        float xv = x1[node * HID + (lane & 15)];   // lane k<16 holds x[k]
        float acc = 0.f;
        #pragma unroll
        for (int k = 0; k < HID; k++) acc += __shfl(xv, k) * wcol[k];
        hg[(size_t)node * HF + c] = acc;
        float vs = acc * ats, vd = acc * atd;
        #pragma unroll
        for (int msk = 8; msk >= 1; msk >>= 1) {
            vs += __shfl_xor(vs, msk);
            vd += __shfl_xor(vd, msk);
        }
        if (ci == 0) {
            a_s[node * HEADS + hh] = vs;
            a_d[node * HEADS + hh] = vd;
        }
    }
}

// h2 = x2(N,192) @ W2(192,16)
__global__ void k_gemm2(const float* __restrict__ x2, const float* __restrict__ W,
                        float* __restrict__ h, int n) {
    __shared__ float sW[HF * HID];
    __shared__ float sX[16][HF + 1];
    int t = threadIdx.x;
    for (int i = t; i < HF * HID; i += 256) sW[i] = W[i];
    int node0 = blockIdx.x * 16;
    for (int i = t; i < 16 * HF; i += 256) {
        int r = i / HF, c = i % HF;
        int node = node0 + r;
        sX[r][c] = (node < n) ? x2[(size_t)node * HF + c] : 0.f;
    }
    __syncthreads();
    int ln = t >> 4, c = t & 15;
    float acc = 0.f;
    #pragma unroll 8
    for (int k = 0; k < HF; k++) acc += sX[ln][k] * sW[k * HID + c];
    int node = node0 + ln;
    if (node < n) h[node * HID + c] = acc;
}

// h3 = x3(N,16) @ W3(16,16)
__global__ void k_gemm3(const float* __restrict__ x3, const float* __restrict__ W,
                        float* __restrict__ h, int n) {
    __shared__ float sW[HID * HID];
    __shared__ float sX[16][HID + 1];
    int t = threadIdx.x;
    sW[t] = W[t];
    int node0 = blockIdx.x * 16;
    int r = t >> 4, cc = t & 15;
    int nd = node0 + r;
    sX[r][cc] = (nd < n) ? x3[nd * HID + cc] : 0.f;
    __syncthreads();
    float acc = 0.f;
    #pragma unroll
    for (int k = 0; k < HID; k++) acc += sX[r][k] * sW[k * HID + cc];
    if (nd < n) h[nd * HID + cc] = acc;
}

// ---------------- Aggregation kernels ----------------

// GCN aggregate: one WAVE per node; lanes = 16 cols x 4 edge slots.
// 4 gathers in flight, serial chain deg/4, shfl_xor merge.
__global__ void k_gcn_agg(const float* __restrict__ h, const int* __restrict__ rowstart,
                          const int* __restrict__ csr, const float* __restrict__ dinv,
                          const float* __restrict__ bias, const float* __restrict__ resid,
                          float* __restrict__ out, int n) {
    int node = (blockIdx.x * blockDim.x + threadIdx.x) >> 6;
    int lane = threadIdx.x & 63;
    if (node >= n) return;
    int c = lane & 15, jj = lane >> 4;
    float dn = dinv[node];
    int base = rowstart[node], deg = rowstart[node + 1] - base;
    float acc = (jj == 0) ? h[node * HID + c] * dn : 0.f;    // self loop
    for (int j = jj; j < deg; j += 4) {
        int s = csr[base + j];
        acc += h[s * HID + c] * dinv[s];
    }
    acc += __shfl_xor(acc, 16);
    acc += __shfl_xor(acc, 32);
    if (lane < 16) {
        float v = fmaxf(acc * dn + bias[c], 0.f);
        if (resid) v += resid[node * HID + c];
        out[node * HID + c] = v;
    }
}

// GAT aggregate: one wave per node; SINGLE fused online-softmax pass with
// defer-max (rescale only when e - m > 8; 1 exp per element per edge),
// 2-edge unroll for memory-level parallelism. Fuses +bg and elu.
__global__ void k_gat_agg(const float* __restrict__ hg, const float* __restrict__ a_s,
                          const float* __restrict__ a_d, const int* __restrict__ rowstart,
                          const int* __restrict__ csr, const float* __restrict__ bg,
                          float* __restrict__ x2, int n) {
    int node = (blockIdx.x * blockDim.x + threadIdx.x) >> 6;
    int lane = threadIdx.x & 63;
    if (node >= n) return;
    int base = rowstart[node], deg = rowstart[node + 1] - base;

    float mh[3], sh[3], acc[3], adh[3];
    int hhv[3];
    #pragma unroll
    for (int it = 0; it < 3; it++) {
        int c = lane + 64 * it;
        int hh = c >> 4;
        hhv[it] = hh;
        float ad = a_d[node * HEADS + hh];
        adh[it] = ad;
        float e = a_s[node * HEADS + hh] + ad;               // self loop
        e = (e > 0.f) ? e : 0.2f * e;
        mh[it] = e;
        sh[it] = 1.f;
        acc[it] = hg[(size_t)node * HF + c];                 // p=1 relative to m=e
    }

    int j = 0;
    for (; j + 2 <= deg; j += 2) {
        int src0 = csr[base + j], src1 = csr[base + j + 1];
        float as0[3], as1[3], hg0[3], hg1[3];
        #pragma unroll
        for (int it = 0; it < 3; it++) {
            as0[it] = a_s[src0 * HEADS + hhv[it]];
            as1[it] = a_s[src1 * HEADS + hhv[it]];
            hg0[it] = hg[(size_t)src0 * HF + lane + 64 * it];
            hg1[it] = hg[(size_t)src1 * HF + lane + 64 * it];
        }
        #pragma unroll
        for (int it = 0; it < 3; it++) {
            float e = as0[it] + adh[it];
            e = (e > 0.f) ? e : 0.2f * e;
            float d = e - mh[it];
            float p = __expf(d);
            if (d > 8.f) {                                   // rare rescale
                float rp = __expf(-d);
                acc[it] = acc[it] * rp + hg0[it];
                sh[it]  = sh[it] * rp + 1.f;
                mh[it] = e;
            } else {
                acc[it] += p * hg0[it];
                sh[it]  += p;
            }
            e = as1[it] + adh[it];
            e = (e > 0.f) ? e : 0.2f * e;
            d = e - mh[it];
            p = __expf(d);
            if (d > 8.f) {
                float rp = __expf(-d);
                acc[it] = acc[it] * rp + hg1[it];
                sh[it]  = sh[it] * rp + 1.f;
                mh[it] = e;
            } else {
                acc[it] += p * hg1[it];
                sh[it]  += p;
            }
        }
    }
    if (j < deg) {                                           // tail (<=1 edge)
        int src0 = csr[base + j];
        #pragma unroll
        for (int it = 0; it < 3; it++) {
            float hgv = hg[(size_t)src0 * HF + lane + 64 * it];
            float e = a_s[src0 * HEADS + hhv[it]] + adh[it];
            e = (e > 0.f) ? e : 0.2f * e;
            float d = e - mh[it];
            float p = __expf(d);
            if (d > 8.f) {
                float rp = __expf(-d);
                acc[it] = acc[it] * rp + hgv;
                sh[it]  = sh[it] * rp + 1.f;
                mh[it] = e;
            } else {
                acc[it] += p * hgv;
                sh[it]  += p;
            }
        }
    }

    #pragma unroll
    for (int it = 0; it < 3; it++) {
        int c = lane + 64 * it;
        float v = acc[it] / sh[it] + bg[c];
        v = (v > 0.f) ? v : (__expf(v) - 1.f);               // elu
        x2[(size_t)node * HF + c] = v;
    }
}

// ---------------- Final reduce + linear ----------------

__global__ void k_mean(const float* __restrict__ x4, float* __restrict__ red, int n) {
    __shared__ float sd[16][17];
    int t = threadIdx.x;
    int ln = t >> 4, c = t & 15;
    float acc = 0.f;
    for (int node = blockIdx.x * 16 + ln; node < n; node += gridDim.x * 16)
        acc += x4[node * HID + c];
    sd[ln][c] = acc;
    __syncthreads();
    for (int off = 8; off >= 1; off >>= 1) {
        if (ln < off) sd[ln][c] += sd[ln + off][c];
        __syncthreads();
    }
    if (ln == 0) atomicAdd(&red[c], sd[0][c]);
}

__global__ void k_final(const float* __restrict__ red, const float* __restrict__ Wlin,
                        const float* __restrict__ blin, float* __restrict__ out, float invN) {
    int o = threadIdx.x;
    if (o >= OUT_C) return;
    float acc = blin[o];
    #pragma unroll
    for (int c = 0; c < HID; c++) acc += (red[c] * invN) * Wlin[c * OUT_C + o];
    out[o] = acc;
}

// ---------------- launch ----------------

extern "C" void kernel_launch(void* const* d_in, const int* in_sizes, int n_in,
                              void* d_out, int out_size, void* d_ws, size_t ws_size,
                              hipStream_t stream) {
    const float* x     = (const float*)d_in[0];
    const void*  ei    = d_in[1];
    const float* W1    = (const float*)d_in[2];
    const float* b1    = (const float*)d_in[3];
    const float* Wg    = (const float*)d_in[4];
    const float* att_s = (const float*)d_in[5];
    const float* att_d = (const float*)d_in[6];
    const float* bg    = (const float*)d_in[7];
    const float* W2    = (const float*)d_in[8];
    const float* b2    = (const float*)d_in[9];
    const float* W3    = (const float*)d_in[10];
    const float* b3    = (const float*)d_in[11];
    const float* Wlin  = (const float*)d_in[12];
    const float* blin  = (const float*)d_in[13];
    float* out = (float*)d_out;

    int N = in_sizes[0] / F_IN;
    int E = in_sizes[1] / 2;

    char* w = (char*)d_ws;
    size_t off = 0;
    auto alloc = [&](size_t bytes) -> void* {
        void* p = w + off;
        off += (bytes + 255) & ~(size_t)255;
        return p;
    };
    int*   flag     = (int*)alloc(256);
    int*   src32    = (int*)alloc((size_t)E * 4);
    int*   dst32    = (int*)alloc((size_t)E * 4);
    int*   count    = (int*)alloc((size_t)N * 4);
    int*   rowstart = (int*)alloc((size_t)(N + 1) * 4);
    int*   cursor   = (int*)alloc((size_t)N * 4);
    int*   csr      = (int*)alloc((size_t)E * 4);
    float* dinv     = (float*)alloc((size_t)N * 4);
    float* h1       = (float*)alloc((size_t)N * HID * 4);
    float* x1       = (float*)alloc((size_t)N * HID * 4);
    float* hg       = (float*)alloc((size_t)N * HF * 4);
    float* a_s      = (float*)alloc((size_t)N * HEADS * 4);
    float* a_d      = (float*)alloc((size_t)N * HEADS * 4);
    float* x2       = (float*)alloc((size_t)N * HF * 4);
    float* h2       = (float*)alloc((size_t)N * HID * 4);
    float* x3       = (float*)alloc((size_t)N * HID * 4);
    float* h3       = (float*)alloc((size_t)N * HID * 4);
    float* x4       = (float*)alloc((size_t)N * HID * 4);
    float* red      = (float*)alloc(64);
    if (off > ws_size) return;

    hipMemsetAsync(flag, 0, 256, stream);
    hipMemsetAsync(count, 0, (size_t)N * 4, stream);
    hipMemsetAsync(cursor, 0, (size_t)N * 4, stream);
    hipMemsetAsync(red, 0, 64, stream);

    int eb = (E + 255) / 256;
    int nb16 = (N + 15) / 16;
    int nbw  = (N + 3) / 4;      // one wave per node, 256-thread blocks

    k_detect<<<1, 256, 0, stream>>>((const int*)ei, E, flag);
    k_convert<<<eb, 256, 0, stream>>>(ei, E, flag, src32, dst32, count);
    k_scan<<<1, 1024, 0, stream>>>(count, rowstart, dinv, N);
    k_fill<<<eb, 256, 0, stream>>>(src32, dst32, E, rowstart, cursor, csr);

    k_gemm1<<<nb16, 256, 0, stream>>>(x, W1, h1, N);
    k_gcn_agg<<<nbw, 256, 0, stream>>>(h1, rowstart, csr, dinv, b1, nullptr, x1, N);

    k_gemm_gat<<<2048, 192, 0, stream>>>(x1, Wg, att_s, att_d, hg, a_s, a_d, N);
    k_gat_agg<<<nbw, 256, 0, stream>>>(hg, a_s, a_d, rowstart, csr, bg, x2, N);

    k_gemm2<<<nb16, 256, 0, stream>>>(x2, W2, h2, N);
    k_gcn_agg<<<nbw, 256, 0, stream>>>(h2, rowstart, csr, dinv, b2, nullptr, x3, N);

    k_gemm3<<<nb16, 256, 0, stream>>>(x3, W3, h3, N);
    k_gcn_agg<<<nbw, 256, 0, stream>>>(h3, rowstart, csr, dinv, b3, x3, x4, N);

    k_mean<<<128, 256, 0, stream>>>(x4, red, N);
    k_final<<<1, 64, 0, stream>>>(red, Wlin, blin, out, 1.0f / (float)N);
}

// Round 9
// 336.108 us; speedup vs baseline: 1.1799x; 1.0450x over previous
//
#include <hip/hip_runtime.h>

#define F_IN 128
#define HID 16
#define HEADS 12
#define HF (HEADS*HID)   // 192
#define OUT_C 32

// ---------------- edge_index dtype probe (self-contained, no pre-zero) ----------------
__global__ void k_detect(const int* __restrict__ ei, int E, int* __restrict__ flag) {
    __shared__ int sacc[256];
    int t = threadIdx.x;                     // single block of 256
    long long half = (long long)E;
    int acc = 0;
    #pragma unroll
    for (int i = 0; i < 8; i++) {
        long long k = ((long long)(t + i * 256) * half) / 2048;
        acc |= ei[2 * k + 1];
    }
    sacc[t] = acc;
    __syncthreads();
    for (int off = 128; off >= 1; off >>= 1) {
        if (t < off) sacc[t] |= sacc[t + off];
        __syncthreads();
    }
    if (t == 0) flag[1] = sacc[0];           // !=0 => data is int32
}

__global__ void k_convert(const void* __restrict__ ei, int E, const int* __restrict__ flag,
                          int* __restrict__ src32, int* __restrict__ dst32,
                          int* __restrict__ count) {
    int e = blockIdx.x * blockDim.x + threadIdx.x;
    if (e >= E) return;
    int s, d;
    if (flag[1] == 0) {                      // int64 layout
        const long long* p = (const long long*)ei;
        s = (int)p[e];
        d = (int)p[(size_t)E + e];
    } else {                                 // int32 layout
        const int* p = (const int*)ei;
        s = p[e];
        d = p[(size_t)E + e];
    }
    src32[e] = s;
    dst32[e] = d;
    atomicAdd(&count[d], 1);
}

// ---------------- CSR build ----------------

__global__ void k_scan(const int* __restrict__ count, int* __restrict__ rowstart,
                       float* __restrict__ dinv, int n) {
    __shared__ int part[1024];
    int t = threadIdx.x;
    int chunk = (n + 1023) >> 10;
    int beg = t * chunk;
    int end = beg + chunk; if (end > n) end = n;
    int s = 0;
    for (int i = beg; i < end; i++) s += count[i];
    part[t] = s;
    __syncthreads();
    for (int off = 1; off < 1024; off <<= 1) {
        int v = (t >= off) ? part[t - off] : 0;
        __syncthreads();
        part[t] += v;
        __syncthreads();
    }
    int run = (t == 0) ? 0 : part[t - 1];
    for (int i = beg; i < end; i++) {
        rowstart[i] = run;
        int c = count[i];
        run += c;
        dinv[i] = rsqrtf((float)(c + 1));   // +1 self loop
    }
    if (t == 1023) rowstart[n] = run;
}

__global__ void k_fill(const int* __restrict__ srcA, const int* __restrict__ dstA, int E,
                       const int* __restrict__ rowstart, int* __restrict__ cursor,
                       int* __restrict__ csr) {
    int e = blockIdx.x * blockDim.x + threadIdx.x;
    if (e < E) {
        int d = dstA[e];
        int p = atomicAdd(&cursor[d], 1);
        csr[rowstart[d] + p] = srcA[e];
    }
}

// ---------------- GEMM kernels ----------------

// h1 = x(N,128) @ W1(128,16)
__global__ void k_gemm1(const float* __restrict__ x, const float* __restrict__ W,
                        float* __restrict__ h, int n) {
    __shared__ float sW[F_IN * HID];
    __shared__ float sX[16][F_IN + 1];
    int t = threadIdx.x;
    for (int i = t; i < F_IN * HID; i += 256) sW[i] = W[i];
    int node0 = blockIdx.x * 16;
    for (int i = t; i < 16 * F_IN; i += 256) {
        int r = i >> 7, c = i & 127;
        int node = node0 + r;
        sX[r][c] = (node < n) ? x[node * F_IN + c] : 0.f;
    }
    __syncthreads();
    int ln = t >> 4, c = t & 15;
    float acc = 0.f;
    #pragma unroll 8
    for (int k = 0; k < F_IN; k++) acc += sX[ln][k] * sW[k * HID + c];
    int node = node0 + ln;
    if (node < n) h[node * HID + c] = acc;
}

// hg = x1(N,16) @ Wg(16,192) + fused attention dots. Persistent, register weights.
__global__ void k_gemm_gat(const float* __restrict__ x1, const float* __restrict__ Wg,
                           const float* __restrict__ att_s, const float* __restrict__ att_d,
                           float* __restrict__ hg, float* __restrict__ a_s,
                           float* __restrict__ a_d, int n) {
    int c = threadIdx.x;          // 0..191 output column
    int lane = c & 63;
    int hh = c >> 4, ci = c & 15;
    float ats = att_s[c];
    float atd = att_d[c];
    float wcol[HID];
    #pragma unroll
    for (int k = 0; k < HID; k++) wcol[k] = Wg[k * HF + c];
    for (int node = blockIdx.x; node < n; node += gridDim.x) {
        float xv = x1[node * HID + (lane & 15)];
        float acc = 0.f;
        #pragma unroll
        for (int k = 0; k < HID; k++) acc += __shfl(xv, k) * wcol[k];
        hg[(size_t)node * HF + c] = acc;
        float vs = acc * ats, vd = acc * atd;
        #pragma unroll
        for (int msk = 8; msk >= 1; msk >>= 1) {
            vs += __shfl_xor(vs, msk);
            vd += __shfl_xor(vd, msk);
        }
        if (ci == 0) {
            a_s[node * HEADS + hh] = vs;
            a_d[node * HEADS + hh] = vd;
        }
    }
}

// h2 = x2(N,192) @ W2(192,16)
__global__ void k_gemm2(const float* __restrict__ x2, const float* __restrict__ W,
                        float* __restrict__ h, int n) {
    __shared__ float sW[HF * HID];
    __shared__ float sX[16][HF + 1];
    int t = threadIdx.x;
    for (int i = t; i < HF * HID; i += 256) sW[i] = W[i];
    int node0 = blockIdx.x * 16;
    for (int i = t; i < 16 * HF; i += 256) {
        int r = i / HF, c = i % HF;
        int node = node0 + r;
        sX[r][c] = (node < n) ? x2[(size_t)node * HF + c] : 0.f;
    }
    __syncthreads();
    int ln = t >> 4, c = t & 15;
    float acc = 0.f;
    #pragma unroll 8
    for (int k = 0; k < HF; k++) acc += sX[ln][k] * sW[k * HID + c];
    int node = node0 + ln;
    if (node < n) h[node * HID + c] = acc;
}

// h3 = x3(N,16) @ W3(16,16)
__global__ void k_gemm3(const float* __restrict__ x3, const float* __restrict__ W,
                        float* __restrict__ h, int n) {
    __shared__ float sW[HID * HID];
    __shared__ float sX[16][HID + 1];
    int t = threadIdx.x;
    sW[t] = W[t];
    int node0 = blockIdx.x * 16;
    int r = t >> 4, cc = t & 15;
    int nd = node0 + r;
    sX[r][cc] = (nd < n) ? x3[nd * HID + cc] : 0.f;
    __syncthreads();
    float acc = 0.f;
    #pragma unroll
    for (int k = 0; k < HID; k++) acc += sX[r][k] * sW[k * HID + cc];
    if (nd < n) h[nd * HID + cc] = acc;
}

// ---------------- Aggregation kernels ----------------

// GCN aggregate: one WAVE per node; lanes = 16 cols x 4 edge slots, 2-edge unroll
// per slot (8 gathers in flight), shfl_xor merge.
__global__ void k_gcn_agg(const float* __restrict__ h, const int* __restrict__ rowstart,
                          const int* __restrict__ csr, const float* __restrict__ dinv,
                          const float* __restrict__ bias, const float* __restrict__ resid,
                          float* __restrict__ out, int n) {
    int node = (blockIdx.x * blockDim.x + threadIdx.x) >> 6;
    int lane = threadIdx.x & 63;
    if (node >= n) return;
    int c = lane & 15, jj = lane >> 4;
    float dn = dinv[node];
    int base = rowstart[node], deg = rowstart[node + 1] - base;
    float acc = (jj == 0) ? h[node * HID + c] * dn : 0.f;    // self loop
    int j = jj;
    for (; j + 4 < deg; j += 8) {
        int s0 = csr[base + j], s1 = csr[base + j + 4];
        float d0 = dinv[s0], d1 = dinv[s1];
        float h0 = h[s0 * HID + c], h1 = h[s1 * HID + c];
        acc += h0 * d0 + h1 * d1;
    }
    if (j < deg) {
        int s0 = csr[base + j];
        acc += h[s0 * HID + c] * dinv[s0];
    }
    acc += __shfl_xor(acc, 16);
    acc += __shfl_xor(acc, 32);
    if (lane < 16) {
        float v = fmaxf(acc * dn + bias[c], 0.f);
        if (resid) v += resid[node * HID + c];
        out[node * HID + c] = v;
    }
}

// GAT aggregate: one wave per node. Head-dedup'd online softmax: lane owns head
// lane%12 (ONE exp wave-instr per edge instead of 3); channel slots fetch p via
// shfl from lanes 0..11. Defer-max rescale = rare wave-wide __any path.
__global__ void k_gat_agg(const float* __restrict__ hg, const float* __restrict__ a_s,
                          const float* __restrict__ a_d, const int* __restrict__ rowstart,
                          const int* __restrict__ csr, const float* __restrict__ bg,
                          float* __restrict__ x2, int n) {
    int node = (blockIdx.x * blockDim.x + threadIdx.x) >> 6;
    int lane = threadIdx.x & 63;
    if (node >= n) return;
    int base = rowstart[node], deg = rowstart[node + 1] - base;

    int hA = lane % 12;                      // softmax head owned by this lane
    int hh0 = lane >> 4;                     // heads feeding the 3 channel slots
    int hh1 = (lane + 64) >> 4;
    int hh2 = (lane + 128) >> 4;

    float adA = a_d[node * HEADS + hA];
    float e0 = a_s[node * HEADS + hA] + adA; // self loop
    e0 = (e0 > 0.f) ? e0 : 0.2f * e0;
    float m = e0, s = 1.f;
    float acc0 = hg[(size_t)node * HF + lane];          // p=1 rel. to m
    float acc1 = hg[(size_t)node * HF + lane + 64];
    float acc2 = hg[(size_t)node * HF + lane + 128];

#define GAT_EDGE(AS, G0, G1, G2)                                      \
    {                                                                 \
        float e = (AS) + adA;                                         \
        e = (e > 0.f) ? e : 0.2f * e;                                 \
        float d = e - m;                                              \
        float p = __expf(d);                                          \
        if (__any(d > 8.f)) {                /* rare rescale */       \
            bool big = d > 8.f;                                       \
            float rp = big ? __expf(-d) : 1.f;                        \
            float pe = big ? 1.f : p;                                 \
            s = s * rp + pe;                                          \
            if (big) m = e;                                           \
            acc0 = acc0 * __shfl(rp, hh0) + __shfl(pe, hh0) * (G0);   \
            acc1 = acc1 * __shfl(rp, hh1) + __shfl(pe, hh1) * (G1);   \
            acc2 = acc2 * __shfl(rp, hh2) + __shfl(pe, hh2) * (G2);   \
        } else {                                                      \
            s += p;                                                   \
            acc0 += __shfl(p, hh0) * (G0);                            \
            acc1 += __shfl(p, hh1) * (G1);                            \
            acc2 += __shfl(p, hh2) * (G2);                            \
        }                                                             \
    }

    int j = 0;
    for (; j + 2 <= deg; j += 2) {
        int s0 = csr[base + j], s1 = csr[base + j + 1];
        float as0 = a_s[s0 * HEADS + hA];
        float as1 = a_s[s1 * HEADS + hA];
        float g00 = hg[(size_t)s0 * HF + lane];
        float g01 = hg[(size_t)s0 * HF + lane + 64];
        float g02 = hg[(size_t)s0 * HF + lane + 128];
        float g10 = hg[(size_t)s1 * HF + lane];
        float g11 = hg[(size_t)s1 * HF + lane + 64];
        float g12 = hg[(size_t)s1 * HF + lane + 128];
        GAT_EDGE(as0, g00, g01, g02)
        GAT_EDGE(as1, g10, g11, g12)
    }
    if (j < deg) {
        int s0 = csr[base + j];
        float as0 = a_s[s0 * HEADS + hA];
        float g00 = hg[(size_t)s0 * HF + lane];
        float g01 = hg[(size_t)s0 * HF + lane + 64];
        float g02 = hg[(size_t)s0 * HF + lane + 128];
        GAT_EDGE(as0, g00, g01, g02)
    }
#undef GAT_EDGE

    float is = 1.f / s;
    float i0 = __shfl(is, hh0), i1 = __shfl(is, hh1), i2 = __shfl(is, hh2);
    float v0 = acc0 * i0 + bg[lane];
    float v1 = acc1 * i1 + bg[lane + 64];
    float v2 = acc2 * i2 + bg[lane + 128];
    v0 = (v0 > 0.f) ? v0 : (__expf(v0) - 1.f);   // elu
    v1 = (v1 > 0.f) ? v1 : (__expf(v1) - 1.f);
    v2 = (v2 > 0.f) ? v2 : (__expf(v2) - 1.f);
    x2[(size_t)node * HF + lane]       = v0;
    x2[(size_t)node * HF + lane + 64]  = v1;
    x2[(size_t)node * HF + lane + 128] = v2;
}

// ---------------- Final reduce + linear ----------------

__global__ void k_mean(const float* __restrict__ x4, float* __restrict__ red, int n) {
    __shared__ float sd[16][17];
    int t = threadIdx.x;
    int ln = t >> 4, c = t & 15;
    float acc = 0.f;
    for (int node = blockIdx.x * 16 + ln; node < n; node += gridDim.x * 16)
        acc += x4[node * HID + c];
    sd[ln][c] = acc;
    __syncthreads();
    for (int off = 8; off >= 1; off >>= 1) {
        if (ln < off) sd[ln][c] += sd[ln + off][c];
        __syncthreads();
    }
    if (ln == 0) atomicAdd(&red[c], sd[0][c]);
}

__global__ void k_final(const float* __restrict__ red, const float* __restrict__ Wlin,
                        const float* __restrict__ blin, float* __restrict__ out, float invN) {
    int o = threadIdx.x;
    if (o >= OUT_C) return;
    float acc = blin[o];
    #pragma unroll
    for (int c = 0; c < HID; c++) acc += (red[c] * invN) * Wlin[c * OUT_C + o];
    out[o] = acc;
}

// ---------------- launch ----------------

extern "C" void kernel_launch(void* const* d_in, const int* in_sizes, int n_in,
                              void* d_out, int out_size, void* d_ws, size_t ws_size,
                              hipStream_t stream) {
    const float* x     = (const float*)d_in[0];
    const void*  ei    = d_in[1];
    const float* W1    = (const float*)d_in[2];
    const float* b1    = (const float*)d_in[3];
    const float* Wg    = (const float*)d_in[4];
    const float* att_s = (const float*)d_in[5];
    const float* att_d = (const float*)d_in[6];
    const float* bg    = (const float*)d_in[7];
    const float* W2    = (const float*)d_in[8];
    const float* b2    = (const float*)d_in[9];
    const float* W3    = (const float*)d_in[10];
    const float* b3    = (const float*)d_in[11];
    const float* Wlin  = (const float*)d_in[12];
    const float* blin  = (const float*)d_in[13];
    float* out = (float*)d_out;

    int N = in_sizes[0] / F_IN;
    int E = in_sizes[1] / 2;

    char* w = (char*)d_ws;
    size_t off = 0;
    auto alloc = [&](size_t bytes) -> void* {
        void* p = w + off;
        off += (bytes + 255) & ~(size_t)255;
        return p;
    };
    int*   flag     = (int*)alloc(256);
    // contiguous zero region: count | cursor | red  (one memset)
    int*   count    = (int*)alloc((size_t)N * 4);
    int*   cursor   = (int*)alloc((size_t)N * 4);
    float* red      = (float*)alloc(64);
    size_t zbytes   = (size_t)((char*)red + 256 - (char*)count);
    int*   src32    = (int*)alloc((size_t)E * 4);
    int*   dst32    = (int*)alloc((size_t)E * 4);
    int*   rowstart = (int*)alloc((size_t)(N + 1) * 4);
    int*   csr      = (int*)alloc((size_t)E * 4);
    float* dinv     = (float*)alloc((size_t)N * 4);
    float* h1       = (float*)alloc((size_t)N * HID * 4);
    float* x1       = (float*)alloc((size_t)N * HID * 4);
    float* hg       = (float*)alloc((size_t)N * HF * 4);
    float* a_s      = (float*)alloc((size_t)N * HEADS * 4);
    float* a_d      = (float*)alloc((size_t)N * HEADS * 4);
    float* x2       = (float*)alloc((size_t)N * HF * 4);
    float* h2       = (float*)alloc((size_t)N * HID * 4);
    float* x3       = (float*)alloc((size_t)N * HID * 4);
    float* h3       = (float*)alloc((size_t)N * HID * 4);
    float* x4       = (float*)alloc((size_t)N * HID * 4);
    if (off > ws_size) return;

    hipMemsetAsync(count, 0, zbytes, stream);    // zeros count+cursor+red in one shot

    int eb = (E + 255) / 256;
    int nb16 = (N + 15) / 16;
    int nbw  = (N + 3) / 4;      // one wave per node, 256-thread blocks

    k_detect<<<1, 256, 0, stream>>>((const int*)ei, E, flag);
    k_convert<<<eb, 256, 0, stream>>>(ei, E, flag, src32, dst32, count);
    k_scan<<<1, 1024, 0, stream>>>(count, rowstart, dinv, N);
    k_fill<<<eb, 256, 0, stream>>>(src32, dst32, E, rowstart, cursor, csr);

    k_gemm1<<<nb16, 256, 0, stream>>>(x, W1, h1, N);
    k_gcn_agg<<<nbw, 256, 0, stream>>>(h1, rowstart, csr, dinv, b1, nullptr, x1, N);

    k_gemm_gat<<<2048, 192, 0, stream>>>(x1, Wg, att_s, att_d, hg, a_s, a_d, N);
    k_gat_agg<<<nbw, 256, 0, stream>>>(hg, a_s, a_d, rowstart, csr, bg, x2, N);

    k_gemm2<<<nb16, 256, 0, stream>>>(x2, W2, h2, N);
    k_gcn_agg<<<nbw, 256, 0, stream>>>(h2, rowstart, csr, dinv, b2, nullptr, x3, N);

    k_gemm3<<<nb16, 256, 0, stream>>>(x3, W3, h3, N);
    k_gcn_agg<<<nbw, 256, 0, stream>>>(h3, rowstart, csr, dinv, b3, x3, x4, N);

    k_mean<<<128, 256, 0, stream>>>(x4, red, N);
    k_final<<<1, 64, 0, stream>>>(red, Wlin, blin, out, 1.0f / (float)N);
}

// Round 12
// 316.318 us; speedup vs baseline: 1.2538x; 1.0626x over previous
//
#include <hip/hip_runtime.h>

#define F_IN 128
#define HID 16
#define HEADS 12
#define HF (HEADS*HID)   // 192
#define OUT_C 32

// ---------------- edge_index dtype probe (self-contained, no pre-zero) ----------------
__global__ void k_detect(const int* __restrict__ ei, int E, int* __restrict__ flag) {
    __shared__ int sacc[256];
    int t = threadIdx.x;                     // single block of 256
    long long half = (long long)E;
    int acc = 0;
    #pragma unroll
    for (int i = 0; i < 8; i++) {
        long long k = ((long long)(t + i * 256) * half) / 2048;
        acc |= ei[2 * k + 1];
    }
    sacc[t] = acc;
    __syncthreads();
    for (int off = 128; off >= 1; off >>= 1) {
        if (t < off) sacc[t] |= sacc[t + off];
        __syncthreads();
    }
    if (t == 0) flag[1] = sacc[0];           // !=0 => data is int32
}

__global__ void k_convert(const void* __restrict__ ei, int E, const int* __restrict__ flag,
                          int* __restrict__ src32, int* __restrict__ dst32,
                          int* __restrict__ count) {
    int e = blockIdx.x * blockDim.x + threadIdx.x;
    if (e >= E) return;
    int s, d;
    if (flag[1] == 0) {                      // int64 layout
        const long long* p = (const long long*)ei;
        s = (int)p[e];
        d = (int)p[(size_t)E + e];
    } else {                                 // int32 layout
        const int* p = (const int*)ei;
        s = p[e];
        d = p[(size_t)E + e];
    }
    src32[e] = s;
    dst32[e] = d;
    atomicAdd(&count[d], 1);
}

// ---------------- CSR build ----------------

__global__ void k_scan(const int* __restrict__ count, int* __restrict__ rowstart,
                       float* __restrict__ dinv, int n) {
    __shared__ int part[1024];
    int t = threadIdx.x;
    int chunk = (n + 1023) >> 10;
    int beg = t * chunk;
    int end = beg + chunk; if (end > n) end = n;
    int s = 0;
    for (int i = beg; i < end; i++) s += count[i];
    part[t] = s;
    __syncthreads();
    for (int off = 1; off < 1024; off <<= 1) {
        int v = (t >= off) ? part[t - off] : 0;
        __syncthreads();
        part[t] += v;
        __syncthreads();
    }
    int run = (t == 0) ? 0 : part[t - 1];
    for (int i = beg; i < end; i++) {
        rowstart[i] = run;
        int c = count[i];
        run += c;
        dinv[i] = rsqrtf((float)(c + 1));   // +1 self loop
    }
    if (t == 1023) rowstart[n] = run;
}

__global__ void k_fill(const int* __restrict__ srcA, const int* __restrict__ dstA, int E,
                       const int* __restrict__ rowstart, int* __restrict__ cursor,
                       int* __restrict__ csr) {
    int e = blockIdx.x * blockDim.x + threadIdx.x;
    if (e < E) {
        int d = dstA[e];
        int p = atomicAdd(&cursor[d], 1);
        csr[rowstart[d] + p] = srcA[e];
    }
}

// ---------------- GEMM kernels ----------------

// h1 = x(N,128) @ W1(128,16)
__global__ void k_gemm1(const float* __restrict__ x, const float* __restrict__ W,
                        float* __restrict__ h, int n) {
    __shared__ float sW[F_IN * HID];
    __shared__ float sX[16][F_IN + 1];
    int t = threadIdx.x;
    for (int i = t; i < F_IN * HID; i += 256) sW[i] = W[i];
    int node0 = blockIdx.x * 16;
    for (int i = t; i < 16 * F_IN; i += 256) {
        int r = i >> 7, c = i & 127;
        int node = node0 + r;
        sX[r][c] = (node < n) ? x[node * F_IN + c] : 0.f;
    }
    __syncthreads();
    int ln = t >> 4, c = t & 15;
    float acc = 0.f;
    #pragma unroll 8
    for (int k = 0; k < F_IN; k++) acc += sX[ln][k] * sW[k * HID + c];
    int node = node0 + ln;
    if (node < n) h[node * HID + c] = acc;
}

// hg = x1(N,16) @ Wg(16,192) + fused attention dots. Persistent, register weights.
__global__ void k_gemm_gat(const float* __restrict__ x1, const float* __restrict__ Wg,
                           const float* __restrict__ att_s, const float* __restrict__ att_d,
                           float* __restrict__ hg, float* __restrict__ a_s,
                           float* __restrict__ a_d, int n) {
    int c = threadIdx.x;          // 0..191 output column
    int lane = c & 63;
    int hh = c >> 4, ci = c & 15;
    float ats = att_s[c];
    float atd = att_d[c];
    float wcol[HID];
    #pragma unroll
    for (int k = 0; k < HID; k++) wcol[k] = Wg[k * HF + c];
    for (int node = blockIdx.x; node < n; node += gridDim.x) {
        float xv = x1[node * HID + (lane & 15)];
        float acc = 0.f;
        #pragma unroll
        for (int k = 0; k < HID; k++) acc += __shfl(xv, k) * wcol[k];
        hg[(size_t)node * HF + c] = acc;
        float vs = acc * ats, vd = acc * atd;
        #pragma unroll
        for (int msk = 8; msk >= 1; msk >>= 1) {
            vs += __shfl_xor(vs, msk);
            vd += __shfl_xor(vd, msk);
        }
        if (ci == 0) {
            a_s[node * HEADS + hh] = vs;
            a_d[node * HEADS + hh] = vd;
        }
    }
}

// ---------------- Aggregation kernels ----------------

// GCN aggregate: one WAVE per node; lanes = 16 cols x 4 edge slots, 2-edge unroll
// per slot (8 gathers in flight). DIRECT csr loads: slot loops have per-lane
// divergent trip counts, so shfl-distributed indices would read inactive lanes (UB).
__global__ void k_gcn_agg(const float* __restrict__ h, const int* __restrict__ rowstart,
                          const int* __restrict__ csr, const float* __restrict__ dinv,
                          const float* __restrict__ bias, const float* __restrict__ resid,
                          float* __restrict__ out, int n) {
    int node = (blockIdx.x * blockDim.x + threadIdx.x) >> 6;
    int lane = threadIdx.x & 63;
    if (node >= n) return;
    int c = lane & 15, jj = lane >> 4;
    float dn = dinv[node];
    int base = rowstart[node], deg = rowstart[node + 1] - base;
    float acc = (jj == 0) ? h[node * HID + c] * dn : 0.f;    // self loop
    int j = jj;
    for (; j + 4 < deg; j += 8) {
        int s0 = csr[base + j], s1 = csr[base + j + 4];
        float d0 = dinv[s0], d1 = dinv[s1];
        float h0 = h[s0 * HID + c], h1 = h[s1 * HID + c];
        acc += h0 * d0 + h1 * d1;
    }
    if (j < deg) {
        int s0 = csr[base + j];
        acc += h[s0 * HID + c] * dinv[s0];
    }
    acc += __shfl_xor(acc, 16);
    acc += __shfl_xor(acc, 32);
    if (lane < 16) {
        float v = fmaxf(acc * dn + bias[c], 0.f);
        if (resid) v += resid[node * HID + c];
        out[node * HID + c] = v;
    }
}

// GCN aggregate layer-2 + fused GEMM3 epilogue: writes x3 AND h3 = x3@W3.
// Aggregation loop = direct csr loads (same divergence reason). Epilogue shfl runs
// with FULL exec (after loop reconvergence) — safe.
__global__ void k_gcn_agg_f3(const float* __restrict__ h, const int* __restrict__ rowstart,
                             const int* __restrict__ csr, const float* __restrict__ dinv,
                             const float* __restrict__ bias, const float* __restrict__ W3,
                             float* __restrict__ x3o, float* __restrict__ h3o, int n) {
    int node = (blockIdx.x * blockDim.x + threadIdx.x) >> 6;
    int lane = threadIdx.x & 63;
    if (node >= n) return;
    int c = lane & 15, jj = lane >> 4;
    float dn = dinv[node];
    int base = rowstart[node], deg = rowstart[node + 1] - base;
    float acc = (jj == 0) ? h[node * HID + c] * dn : 0.f;
    int j = jj;
    for (; j + 4 < deg; j += 8) {
        int s0 = csr[base + j], s1 = csr[base + j + 4];
        float d0 = dinv[s0], d1 = dinv[s1];
        float h0 = h[s0 * HID + c], h1 = h[s1 * HID + c];
        acc += h0 * d0 + h1 * d1;
    }
    if (j < deg) {
        int s0 = csr[base + j];
        acc += h[s0 * HID + c] * dinv[s0];
    }
    acc += __shfl_xor(acc, 16);
    acc += __shfl_xor(acc, 32);
    // all lanes hold the full sum for channel c (full exec from here on)
    float v = fmaxf(acc * dn + bias[c], 0.f);
    if (lane < 16) x3o[node * HID + c] = v;
    // h3[c'] = sum_cc v(cc) * W3[cc][c'] ; exchange v within own 16-lane group
    int gbase = lane & 48;
    float hacc = 0.f;
    #pragma unroll
    for (int cc = 0; cc < 16; cc++)
        hacc += __shfl(v, gbase | cc) * W3[cc * HID + c];
    if (lane < 16) h3o[node * HID + c] = hacc;
}

// GAT aggregate + fused GEMM2 epilogue: one wave per node. Head-dedup'd online
// softmax (lane owns head lane%12); csr row wave-preloaded (j is WAVE-UNIFORM here,
// so shfl sources are always active — safe); 4-edge pipeline. Epilogue computes x2
// (192 ch in-reg) then h2 = x2@W2 via butterfly — x2 never hits memory.
__global__ void k_gat_agg(const float* __restrict__ hg, const float* __restrict__ a_s,
                          const float* __restrict__ a_d, const int* __restrict__ rowstart,
                          const int* __restrict__ csr, const float* __restrict__ bg,
                          const float* __restrict__ W2, float* __restrict__ h2, int n) {
    int node = (blockIdx.x * blockDim.x + threadIdx.x) >> 6;
    int lane = threadIdx.x & 63;
    if (node >= n) return;
    int base = rowstart[node], deg = rowstart[node + 1] - base;
    int dcap = deg < 64 ? deg : 64;
    int eidx = (lane < dcap) ? csr[base + lane] : 0;

    int hA = lane % 12;                      // softmax head owned by this lane
    int hh0 = lane >> 4;                     // heads feeding the 3 channel slots
    int hh1 = (lane + 64) >> 4;
    int hh2 = (lane + 128) >> 4;

    float adA = a_d[node * HEADS + hA];
    float e0 = a_s[node * HEADS + hA] + adA; // self loop
    e0 = (e0 > 0.f) ? e0 : 0.2f * e0;
    float m = e0, s = 1.f;
    float acc0 = hg[(size_t)node * HF + lane];          // p=1 rel. to m
    float acc1 = hg[(size_t)node * HF + lane + 64];
    float acc2 = hg[(size_t)node * HF + lane + 128];

#define GAT_EDGE(AS, G0, G1, G2)                                      \
    {                                                                 \
        float e = (AS) + adA;                                         \
        e = (e > 0.f) ? e : 0.2f * e;                                 \
        float d = e - m;                                              \
        float p = __expf(d);                                          \
        if (__any(d > 8.f)) {                /* rare rescale */       \
            bool big = d > 8.f;                                       \
            float rp = big ? __expf(-d) : 1.f;                        \
            float pe = big ? 1.f : p;                                 \
            s = s * rp + pe;                                          \
            if (big) m = e;                                           \
            acc0 = acc0 * __shfl(rp, hh0) + __shfl(pe, hh0) * (G0);   \
            acc1 = acc1 * __shfl(rp, hh1) + __shfl(pe, hh1) * (G1);   \
            acc2 = acc2 * __shfl(rp, hh2) + __shfl(pe, hh2) * (G2);   \
        } else {                                                      \
            s += p;                                                   \
            acc0 += __shfl(p, hh0) * (G0);                            \
            acc1 += __shfl(p, hh1) * (G1);                            \
            acc2 += __shfl(p, hh2) * (G2);                            \
        }                                                             \
    }

    int j = 0;
    for (; j + 4 <= dcap; j += 4) {          // 4-edge pipeline, 16 gathers in flight
        int s0 = __shfl(eidx, j),     s1 = __shfl(eidx, j + 1);
        int s2 = __shfl(eidx, j + 2), s3 = __shfl(eidx, j + 3);
        float A0 = a_s[s0 * HEADS + hA], A1 = a_s[s1 * HEADS + hA];
        float A2 = a_s[s2 * HEADS + hA], A3 = a_s[s3 * HEADS + hA];
        float g00 = hg[(size_t)s0 * HF + lane], g01 = hg[(size_t)s0 * HF + lane + 64], g02 = hg[(size_t)s0 * HF + lane + 128];
        float g10 = hg[(size_t)s1 * HF + lane], g11 = hg[(size_t)s1 * HF + lane + 64], g12 = hg[(size_t)s1 * HF + lane + 128];
        float g20 = hg[(size_t)s2 * HF + lane], g21 = hg[(size_t)s2 * HF + lane + 64], g22 = hg[(size_t)s2 * HF + lane + 128];
        float g30 = hg[(size_t)s3 * HF + lane], g31 = hg[(size_t)s3 * HF + lane + 64], g32 = hg[(size_t)s3 * HF + lane + 128];
        GAT_EDGE(A0, g00, g01, g02)
        GAT_EDGE(A1, g10, g11, g12)
        GAT_EDGE(A2, g20, g21, g22)
        GAT_EDGE(A3, g30, g31, g32)
    }
    for (; j < dcap; j++) {                  // tail (<=3 edges), wave-uniform j
        int s0 = __shfl(eidx, j);
        float A0 = a_s[s0 * HEADS + hA];
        float g00 = hg[(size_t)s0 * HF + lane], g01 = hg[(size_t)s0 * HF + lane + 64], g02 = hg[(size_t)s0 * HF + lane + 128];
        GAT_EDGE(A0, g00, g01, g02)
    }
    for (; j < deg; j++) {                   // deg>64 fallback (≈never), wave-uniform
        int s0 = csr[base + j];
        float A0 = a_s[s0 * HEADS + hA];
        float g00 = hg[(size_t)s0 * HF + lane], g01 = hg[(size_t)s0 * HF + lane + 64], g02 = hg[(size_t)s0 * HF + lane + 128];
        GAT_EDGE(A0, g00, g01, g02)
    }
#undef GAT_EDGE

    float is = 1.f / s;
    float i0 = __shfl(is, hh0), i1 = __shfl(is, hh1), i2 = __shfl(is, hh2);
    float v0 = acc0 * i0 + bg[lane];
    float v1 = acc1 * i1 + bg[lane + 64];
    float v2 = acc2 * i2 + bg[lane + 128];
    v0 = (v0 > 0.f) ? v0 : (__expf(v0) - 1.f);   // elu -> x2 values (in-reg only)
    v1 = (v1 > 0.f) ? v1 : (__expf(v1) - 1.f);
    v2 = (v2 > 0.f) ? v2 : (__expf(v2) - 1.f);

    // fused GEMM2: h2[c'] = sum_k x2[k]*W2[k][c'] ; lane holds k = lane,+64,+128
    float p[16];
    const float4* W2v = (const float4*)W2;       // [192][16] -> [192][4] float4
    #pragma unroll
    for (int q = 0; q < 4; q++) {
        float4 w0 = W2v[lane * 4 + q];
        float4 w1 = W2v[(lane + 64) * 4 + q];
        float4 w2 = W2v[(lane + 128) * 4 + q];
        p[q * 4 + 0] = v0 * w0.x + v1 * w1.x + v2 * w2.x;
        p[q * 4 + 1] = v0 * w0.y + v1 * w1.y + v2 * w2.y;
        p[q * 4 + 2] = v0 * w0.z + v1 * w1.z + v2 * w2.z;
        p[q * 4 + 3] = v0 * w0.w + v1 * w1.w + v2 * w2.w;
    }
    #pragma unroll
    for (int mask = 1; mask <= 32; mask <<= 1) {
        #pragma unroll
        for (int cq = 0; cq < 16; cq++) p[cq] += __shfl_xor(p[cq], mask);
    }
    if (lane < 16) h2[node * HID + lane] = p[lane];
}

// ---------------- Final reduce + linear ----------------

__global__ void k_mean(const float* __restrict__ x4, float* __restrict__ red, int n) {
    __shared__ float sd[16][17];
    int t = threadIdx.x;
    int ln = t >> 4, c = t & 15;
    float acc = 0.f;
    for (int node = blockIdx.x * 16 + ln; node < n; node += gridDim.x * 16)
        acc += x4[node * HID + c];
    sd[ln][c] = acc;
    __syncthreads();
    for (int off = 8; off >= 1; off >>= 1) {
        if (ln < off) sd[ln][c] += sd[ln + off][c];
        __syncthreads();
    }
    if (ln == 0) atomicAdd(&red[c], sd[0][c]);
}

__global__ void k_final(const float* __restrict__ red, const float* __restrict__ Wlin,
                        const float* __restrict__ blin, float* __restrict__ out, float invN) {
    int o = threadIdx.x;
    if (o >= OUT_C) return;
    float acc = blin[o];
    #pragma unroll
    for (int c = 0; c < HID; c++) acc += (red[c] * invN) * Wlin[c * OUT_C + o];
    out[o] = acc;
}

// ---------------- launch ----------------

extern "C" void kernel_launch(void* const* d_in, const int* in_sizes, int n_in,
                              void* d_out, int out_size, void* d_ws, size_t ws_size,
                              hipStream_t stream) {
    const float* x     = (const float*)d_in[0];
    const void*  ei    = d_in[1];
    const float* W1    = (const float*)d_in[2];
    const float* b1    = (const float*)d_in[3];
    const float* Wg    = (const float*)d_in[4];
    const float* att_s = (const float*)d_in[5];
    const float* att_d = (const float*)d_in[6];
    const float* bg    = (const float*)d_in[7];
    const float* W2    = (const float*)d_in[8];
    const float* b2    = (const float*)d_in[9];
    const float* W3    = (const float*)d_in[10];
    const float* b3    = (const float*)d_in[11];
    const float* Wlin  = (const float*)d_in[12];
    const float* blin  = (const float*)d_in[13];
    float* out = (float*)d_out;

    int N = in_sizes[0] / F_IN;
    int E = in_sizes[1] / 2;

    char* w = (char*)d_ws;
    size_t off = 0;
    auto alloc = [&](size_t bytes) -> void* {
        void* p = w + off;
        off += (bytes + 255) & ~(size_t)255;
        return p;
    };
    int*   flag     = (int*)alloc(256);
    // contiguous zero region: count | cursor | red  (one memset)
    int*   count    = (int*)alloc((size_t)N * 4);
    int*   cursor   = (int*)alloc((size_t)N * 4);
    float* red      = (float*)alloc(64);
    size_t zbytes   = (size_t)((char*)red + 256 - (char*)count);
    int*   src32    = (int*)alloc((size_t)E * 4);
    int*   dst32    = (int*)alloc((size_t)E * 4);
    int*   rowstart = (int*)alloc((size_t)(N + 1) * 4);
    int*   csr      = (int*)alloc((size_t)E * 4);
    float* dinv     = (float*)alloc((size_t)N * 4);
    float* h1       = (float*)alloc((size_t)N * HID * 4);
    float* x1       = (float*)alloc((size_t)N * HID * 4);
    float* hg       = (float*)alloc((size_t)N * HF * 4);
    float* a_s      = (float*)alloc((size_t)N * HEADS * 4);
    float* a_d      = (float*)alloc((size_t)N * HEADS * 4);
    float* h2       = (float*)alloc((size_t)N * HID * 4);
    float* x3       = (float*)alloc((size_t)N * HID * 4);
    float* h3       = (float*)alloc((size_t)N * HID * 4);
    float* x4       = (float*)alloc((size_t)N * HID * 4);
    if (off > ws_size) return;

    hipMemsetAsync(count, 0, zbytes, stream);    // zeros count+cursor+red in one shot

    int eb = (E + 255) / 256;
    int nb16 = (N + 15) / 16;
    int nbw  = (N + 3) / 4;      // one wave per node, 256-thread blocks

    k_detect<<<1, 256, 0, stream>>>((const int*)ei, E, flag);
    k_convert<<<eb, 256, 0, stream>>>(ei, E, flag, src32, dst32, count);
    k_scan<<<1, 1024, 0, stream>>>(count, rowstart, dinv, N);
    k_fill<<<eb, 256, 0, stream>>>(src32, dst32, E, rowstart, cursor, csr);

    k_gemm1<<<nb16, 256, 0, stream>>>(x, W1, h1, N);
    k_gcn_agg<<<nbw, 256, 0, stream>>>(h1, rowstart, csr, dinv, b1, nullptr, x1, N);

    k_gemm_gat<<<2048, 192, 0, stream>>>(x1, Wg, att_s, att_d, hg, a_s, a_d, N);
    k_gat_agg<<<nbw, 256, 0, stream>>>(hg, a_s, a_d, rowstart, csr, bg, W2, h2, N);

    k_gcn_agg_f3<<<nbw, 256, 0, stream>>>(h2, rowstart, csr, dinv, b2, W3, x3, h3, N);
    k_gcn_agg<<<nbw, 256, 0, stream>>>(h3, rowstart, csr, dinv, b3, x3, x4, N);

    k_mean<<<128, 256, 0, stream>>>(x4, red, N);
    k_final<<<1, 64, 0, stream>>>(red, Wlin, blin, out, 1.0f / (float)N);
}

// Round 13
// 314.858 us; speedup vs baseline: 1.2596x; 1.0046x over previous
//
#include <hip/hip_runtime.h>

#define F_IN 128
#define HID 16
#define HEADS 12
#define HF (HEADS*HID)   // 192
#define OUT_C 32

typedef _Float16 f16;

// ---------------- edge_index dtype probe (self-contained, no pre-zero) ----------------
__global__ void k_detect(const int* __restrict__ ei, int E, int* __restrict__ flag) {
    __shared__ int sacc[256];
    int t = threadIdx.x;
    long long half = (long long)E;
    int acc = 0;
    #pragma unroll
    for (int i = 0; i < 8; i++) {
        long long k = ((long long)(t + i * 256) * half) / 2048;
        acc |= ei[2 * k + 1];
    }
    sacc[t] = acc;
    __syncthreads();
    for (int off = 128; off >= 1; off >>= 1) {
        if (t < off) sacc[t] |= sacc[t + off];
        __syncthreads();
    }
    if (t == 0) flag[1] = sacc[0];           // !=0 => data is int32
}

__global__ void k_convert(const void* __restrict__ ei, int E, const int* __restrict__ flag,
                          int* __restrict__ src32, int* __restrict__ dst32,
                          int* __restrict__ count) {
    int e = blockIdx.x * blockDim.x + threadIdx.x;
    if (e >= E) return;
    int s, d;
    if (flag[1] == 0) {                      // int64 layout
        const long long* p = (const long long*)ei;
        s = (int)p[e];
        d = (int)p[(size_t)E + e];
    } else {                                 // int32 layout
        const int* p = (const int*)ei;
        s = p[e];
        d = p[(size_t)E + e];
    }
    src32[e] = s;
    dst32[e] = d;
    atomicAdd(&count[d], 1);
}

// ---------------- CSR build ----------------

__global__ void k_scan(const int* __restrict__ count, int* __restrict__ rowstart,
                       float* __restrict__ dinv, int n) {
    __shared__ int part[1024];
    int t = threadIdx.x;
    int chunk = (n + 1023) >> 10;
    int beg = t * chunk;
    int end = beg + chunk; if (end > n) end = n;
    int s = 0;
    for (int i = beg; i < end; i++) s += count[i];
    part[t] = s;
    __syncthreads();
    for (int off = 1; off < 1024; off <<= 1) {
        int v = (t >= off) ? part[t - off] : 0;
        __syncthreads();
        part[t] += v;
        __syncthreads();
    }
    int run = (t == 0) ? 0 : part[t - 1];
    for (int i = beg; i < end; i++) {
        rowstart[i] = run;
        int c = count[i];
        run += c;
        dinv[i] = rsqrtf((float)(c + 1));   // +1 self loop
    }
    if (t == 1023) rowstart[n] = run;
}

__global__ void k_fill(const int* __restrict__ srcA, const int* __restrict__ dstA, int E,
                       const int* __restrict__ rowstart, int* __restrict__ cursor,
                       int* __restrict__ csr) {
    int e = blockIdx.x * blockDim.x + threadIdx.x;
    if (e < E) {
        int d = dstA[e];
        int p = atomicAdd(&cursor[d], 1);
        csr[rowstart[d] + p] = srcA[e];
    }
}

// ---------------- GEMM kernels ----------------

// h1 = x(N,128) @ W1(128,16) -> fp16 (gathered later; mean-pool washes fp16 noise)
__global__ void k_gemm1(const float* __restrict__ x, const float* __restrict__ W,
                        f16* __restrict__ h, int n) {
    __shared__ float sW[F_IN * HID];
    __shared__ float sX[16][F_IN + 1];
    int t = threadIdx.x;
    for (int i = t; i < F_IN * HID; i += 256) sW[i] = W[i];
    int node0 = blockIdx.x * 16;
    for (int i = t; i < 16 * F_IN; i += 256) {
        int r = i >> 7, c = i & 127;
        int node = node0 + r;
        sX[r][c] = (node < n) ? x[node * F_IN + c] : 0.f;
    }
    __syncthreads();
    int ln = t >> 4, c = t & 15;
    float acc = 0.f;
    #pragma unroll 8
    for (int k = 0; k < F_IN; k++) acc += sX[ln][k] * sW[k * HID + c];
    int node = node0 + ln;
    if (node < n) h[node * HID + c] = (f16)acc;
}

// hg = x1(N,16) @ Wg(16,192) + fused attention dots. hg stored fp16; a_s/a_d fp32.
__global__ void k_gemm_gat(const float* __restrict__ x1, const float* __restrict__ Wg,
                           const float* __restrict__ att_s, const float* __restrict__ att_d,
                           f16* __restrict__ hg, float* __restrict__ a_s,
                           float* __restrict__ a_d, int n) {
    int c = threadIdx.x;          // 0..191 output column
    int lane = c & 63;
    int hh = c >> 4, ci = c & 15;
    float ats = att_s[c];
    float atd = att_d[c];
    float wcol[HID];
    #pragma unroll
    for (int k = 0; k < HID; k++) wcol[k] = Wg[k * HF + c];
    for (int node = blockIdx.x; node < n; node += gridDim.x) {
        float xv = x1[node * HID + (lane & 15)];
        float acc = 0.f;
        #pragma unroll
        for (int k = 0; k < HID; k++) acc += __shfl(xv, k) * wcol[k];
        hg[(size_t)node * HF + c] = (f16)acc;
        float vs = acc * ats, vd = acc * atd;
        #pragma unroll
        for (int msk = 8; msk >= 1; msk >>= 1) {
            vs += __shfl_xor(vs, msk);
            vd += __shfl_xor(vd, msk);
        }
        if (ci == 0) {
            a_s[node * HEADS + hh] = vs;
            a_d[node * HEADS + hh] = vd;
        }
    }
}

// ---------------- Aggregation kernels ----------------

// GCN aggregate: one WAVE per node; 16 cols x 4 edge slots, 2-edge unroll.
// h input fp16 (32B/row gather). Direct csr loads (divergent trip counts).
__global__ void k_gcn_agg(const f16* __restrict__ h, const int* __restrict__ rowstart,
                          const int* __restrict__ csr, const float* __restrict__ dinv,
                          const float* __restrict__ bias, const float* __restrict__ resid,
                          float* __restrict__ out, int n) {
    int node = (blockIdx.x * blockDim.x + threadIdx.x) >> 6;
    int lane = threadIdx.x & 63;
    if (node >= n) return;
    int c = lane & 15, jj = lane >> 4;
    float dn = dinv[node];
    int base = rowstart[node], deg = rowstart[node + 1] - base;
    float acc = (jj == 0) ? (float)h[node * HID + c] * dn : 0.f;   // self loop
    int j = jj;
    for (; j + 4 < deg; j += 8) {
        int s0 = csr[base + j], s1 = csr[base + j + 4];
        float d0 = dinv[s0], d1 = dinv[s1];
        float h0 = (float)h[s0 * HID + c], h1 = (float)h[s1 * HID + c];
        acc += h0 * d0 + h1 * d1;
    }
    if (j < deg) {
        int s0 = csr[base + j];
        acc += (float)h[s0 * HID + c] * dinv[s0];
    }
    acc += __shfl_xor(acc, 16);
    acc += __shfl_xor(acc, 32);
    if (lane < 16) {
        float v = fmaxf(acc * dn + bias[c], 0.f);
        if (resid) v += resid[node * HID + c];
        out[node * HID + c] = v;
    }
}

// GCN aggregate layer-2 + fused GEMM3 epilogue: writes x3 (fp32) AND h3 = x3@W3 (fp16).
__global__ void k_gcn_agg_f3(const f16* __restrict__ h, const int* __restrict__ rowstart,
                             const int* __restrict__ csr, const float* __restrict__ dinv,
                             const float* __restrict__ bias, const float* __restrict__ W3,
                             float* __restrict__ x3o, f16* __restrict__ h3o, int n) {
    int node = (blockIdx.x * blockDim.x + threadIdx.x) >> 6;
    int lane = threadIdx.x & 63;
    if (node >= n) return;
    int c = lane & 15, jj = lane >> 4;
    float dn = dinv[node];
    int base = rowstart[node], deg = rowstart[node + 1] - base;
    float acc = (jj == 0) ? (float)h[node * HID + c] * dn : 0.f;
    int j = jj;
    for (; j + 4 < deg; j += 8) {
        int s0 = csr[base + j], s1 = csr[base + j + 4];
        float d0 = dinv[s0], d1 = dinv[s1];
        float h0 = (float)h[s0 * HID + c], h1 = (float)h[s1 * HID + c];
        acc += h0 * d0 + h1 * d1;
    }
    if (j < deg) {
        int s0 = csr[base + j];
        acc += (float)h[s0 * HID + c] * dinv[s0];
    }
    acc += __shfl_xor(acc, 16);
    acc += __shfl_xor(acc, 32);
    // all lanes hold the full sum for channel c (full exec from here on)
    float v = fmaxf(acc * dn + bias[c], 0.f);
    if (lane < 16) x3o[node * HID + c] = v;
    int gbase = lane & 48;
    float hacc = 0.f;
    #pragma unroll
    for (int cc = 0; cc < 16; cc++)
        hacc += __shfl(v, gbase | cc) * W3[cc * HID + c];
    if (lane < 16) h3o[node * HID + c] = (f16)hacc;
}

// GAT aggregate + fused GEMM2 epilogue. hg fp16 gathers (6 lines/edge instead of 12).
// csr wave-preload (j wave-uniform -> shfl safe); 4-edge pipeline. h2 out fp16.
// p[] selection via cndmask ladder (NO dynamic register index -> no scratch).
__global__ void k_gat_agg(const f16* __restrict__ hg, const float* __restrict__ a_s,
                          const float* __restrict__ a_d, const int* __restrict__ rowstart,
                          const int* __restrict__ csr, const float* __restrict__ bg,
                          const float* __restrict__ W2, f16* __restrict__ h2, int n) {
    int node = (blockIdx.x * blockDim.x + threadIdx.x) >> 6;
    int lane = threadIdx.x & 63;
    if (node >= n) return;
    int base = rowstart[node], deg = rowstart[node + 1] - base;
    int dcap = deg < 64 ? deg : 64;
    int eidx = (lane < dcap) ? csr[base + lane] : 0;

    int hA = lane % 12;
    int hh0 = lane >> 4;
    int hh1 = (lane + 64) >> 4;
    int hh2 = (lane + 128) >> 4;

    float adA = a_d[node * HEADS + hA];
    float e0 = a_s[node * HEADS + hA] + adA; // self loop
    e0 = (e0 > 0.f) ? e0 : 0.2f * e0;
    float m = e0, s = 1.f;
    float acc0 = (float)hg[(size_t)node * HF + lane];
    float acc1 = (float)hg[(size_t)node * HF + lane + 64];
    float acc2 = (float)hg[(size_t)node * HF + lane + 128];

#define GAT_EDGE(AS, G0, G1, G2)                                      \
    {                                                                 \
        float e = (AS) + adA;                                         \
        e = (e > 0.f) ? e : 0.2f * e;                                 \
        float d = e - m;                                              \
        float p = __expf(d);                                          \
        if (__any(d > 8.f)) {                /* rare rescale */       \
            bool big = d > 8.f;                                       \
            float rp = big ? __expf(-d) : 1.f;                        \
            float pe = big ? 1.f : p;                                 \
            s = s * rp + pe;                                          \
            if (big) m = e;                                           \
            acc0 = acc0 * __shfl(rp, hh0) + __shfl(pe, hh0) * (G0);   \
            acc1 = acc1 * __shfl(rp, hh1) + __shfl(pe, hh1) * (G1);   \
            acc2 = acc2 * __shfl(rp, hh2) + __shfl(pe, hh2) * (G2);   \
        } else {                                                      \
            s += p;                                                   \
            acc0 += __shfl(p, hh0) * (G0);                            \
            acc1 += __shfl(p, hh1) * (G1);                            \
            acc2 += __shfl(p, hh2) * (G2);                            \
        }                                                             \
    }

    int j = 0;
    for (; j + 4 <= dcap; j += 4) {
        int s0 = __shfl(eidx, j),     s1 = __shfl(eidx, j + 1);
        int s2 = __shfl(eidx, j + 2), s3 = __shfl(eidx, j + 3);
        float A0 = a_s[s0 * HEADS + hA], A1 = a_s[s1 * HEADS + hA];
        float A2 = a_s[s2 * HEADS + hA], A3 = a_s[s3 * HEADS + hA];
        float g00 = (float)hg[(size_t)s0 * HF + lane], g01 = (float)hg[(size_t)s0 * HF + lane + 64], g02 = (float)hg[(size_t)s0 * HF + lane + 128];
        float g10 = (float)hg[(size_t)s1 * HF + lane], g11 = (float)hg[(size_t)s1 * HF + lane + 64], g12 = (float)hg[(size_t)s1 * HF + lane + 128];
        float g20 = (float)hg[(size_t)s2 * HF + lane], g21 = (float)hg[(size_t)s2 * HF + lane + 64], g22 = (float)hg[(size_t)s2 * HF + lane + 128];
        float g30 = (float)hg[(size_t)s3 * HF + lane], g31 = (float)hg[(size_t)s3 * HF + lane + 64], g32 = (float)hg[(size_t)s3 * HF + lane + 128];
        GAT_EDGE(A0, g00, g01, g02)
        GAT_EDGE(A1, g10, g11, g12)
        GAT_EDGE(A2, g20, g21, g22)
        GAT_EDGE(A3, g30, g31, g32)
    }
    for (; j < dcap; j++) {                  // tail, wave-uniform j
        int s0 = __shfl(eidx, j);
        float A0 = a_s[s0 * HEADS + hA];
        float g00 = (float)hg[(size_t)s0 * HF + lane], g01 = (float)hg[(size_t)s0 * HF + lane + 64], g02 = (float)hg[(size_t)s0 * HF + lane + 128];
        GAT_EDGE(A0, g00, g01, g02)
    }
    for (; j < deg; j++) {                   // deg>64 fallback, wave-uniform
        int s0 = csr[base + j];
        float A0 = a_s[s0 * HEADS + hA];
        float g00 = (float)hg[(size_t)s0 * HF + lane], g01 = (float)hg[(size_t)s0 * HF + lane + 64], g02 = (float)hg[(size_t)s0 * HF + lane + 128];
        GAT_EDGE(A0, g00, g01, g02)
    }
#undef GAT_EDGE

    float is = 1.f / s;
    float i0 = __shfl(is, hh0), i1 = __shfl(is, hh1), i2 = __shfl(is, hh2);
    float v0 = acc0 * i0 + bg[lane];
    float v1 = acc1 * i1 + bg[lane + 64];
    float v2 = acc2 * i2 + bg[lane + 128];
    v0 = (v0 > 0.f) ? v0 : (__expf(v0) - 1.f);   // elu -> x2 (in-reg only)
    v1 = (v1 > 0.f) ? v1 : (__expf(v1) - 1.f);
    v2 = (v2 > 0.f) ? v2 : (__expf(v2) - 1.f);

    // fused GEMM2: h2[c'] = sum_k x2[k]*W2[k][c']
    float p[16];
    const float4* W2v = (const float4*)W2;       // [192][16] -> [192][4] float4
    #pragma unroll
    for (int q = 0; q < 4; q++) {
        float4 w0 = W2v[lane * 4 + q];
        float4 w1 = W2v[(lane + 64) * 4 + q];
        float4 w2 = W2v[(lane + 128) * 4 + q];
        p[q * 4 + 0] = v0 * w0.x + v1 * w1.x + v2 * w2.x;
        p[q * 4 + 1] = v0 * w0.y + v1 * w1.y + v2 * w2.y;
        p[q * 4 + 2] = v0 * w0.z + v1 * w1.z + v2 * w2.z;
        p[q * 4 + 3] = v0 * w0.w + v1 * w1.w + v2 * w2.w;
    }
    #pragma unroll
    for (int mask = 1; mask <= 32; mask <<= 1) {
        #pragma unroll
        for (int cq = 0; cq < 16; cq++) p[cq] += __shfl_xor(p[cq], mask);
    }
    // static-index selection (cndmask ladder) — keeps p in VGPRs
    float vout = p[0];
    #pragma unroll
    for (int q = 1; q < 16; q++) vout = (lane == q) ? p[q] : vout;
    if (lane < 16) h2[node * HID + lane] = (f16)vout;
}

// ---------------- Fused mean + final linear (last-block pattern) ----------------

__global__ void k_mean_final(const float* __restrict__ x4, float* __restrict__ red,
                             int* __restrict__ done, const float* __restrict__ Wlin,
                             const float* __restrict__ blin, float* __restrict__ out,
                             float invN, int n, int nblocks) {
    __shared__ float sd[16][17];
    __shared__ float sred[16];
    __shared__ int slast;
    int t = threadIdx.x;
    int ln = t >> 4, c = t & 15;
    float acc = 0.f;
    for (int node = blockIdx.x * 16 + ln; node < n; node += gridDim.x * 16)
        acc += x4[node * HID + c];
    sd[ln][c] = acc;
    __syncthreads();
    for (int off = 8; off >= 1; off >>= 1) {
        if (ln < off) sd[ln][c] += sd[ln + off][c];
        __syncthreads();
    }
    if (ln == 0) atomicAdd(&red[c], sd[0][c]);
    __threadfence();
    __syncthreads();
    if (t == 0) slast = (atomicAdd(done, 1) == nblocks - 1);
    __syncthreads();
    if (slast) {                              // block-uniform condition
        if (t < 16) sred[t] = atomicAdd(&red[t], 0.0f);   // coherent read via atomic
        __syncthreads();
        if (t < OUT_C) {
            float a = blin[t];
            #pragma unroll
            for (int cc = 0; cc < HID; cc++) a += (sred[cc] * invN) * Wlin[cc * OUT_C + t];
            out[t] = a;
        }
    }
}

// ---------------- launch ----------------

extern "C" void kernel_launch(void* const* d_in, const int* in_sizes, int n_in,
                              void* d_out, int out_size, void* d_ws, size_t ws_size,
                              hipStream_t stream) {
    const float* x     = (const float*)d_in[0];
    const void*  ei    = d_in[1];
    const float* W1    = (const float*)d_in[2];
    const float* b1    = (const float*)d_in[3];
    const float* Wg    = (const float*)d_in[4];
    const float* att_s = (const float*)d_in[5];
    const float* att_d = (const float*)d_in[6];
    const float* bg    = (const float*)d_in[7];
    const float* W2    = (const float*)d_in[8];
    const float* b2    = (const float*)d_in[9];
    const float* W3    = (const float*)d_in[10];
    const float* b3    = (const float*)d_in[11];
    const float* Wlin  = (const float*)d_in[12];
    const float* blin  = (const float*)d_in[13];
    float* out = (float*)d_out;

    int N = in_sizes[0] / F_IN;
    int E = in_sizes[1] / 2;

    char* w = (char*)d_ws;
    size_t off = 0;
    auto alloc = [&](size_t bytes) -> void* {
        void* p = w + off;
        off += (bytes + 255) & ~(size_t)255;
        return p;
    };
    int*   flag     = (int*)alloc(256);
    // contiguous zero region: count | cursor | red+done  (one memset)
    int*   count    = (int*)alloc((size_t)N * 4);
    int*   cursor   = (int*)alloc((size_t)N * 4);
    float* red      = (float*)alloc(256);          // red[16] + done
    int*   done     = (int*)((char*)red + 64);
    size_t zbytes   = (size_t)((char*)red + 256 - (char*)count);
    int*   src32    = (int*)alloc((size_t)E * 4);
    int*   dst32    = (int*)alloc((size_t)E * 4);
    int*   rowstart = (int*)alloc((size_t)(N + 1) * 4);
    int*   csr      = (int*)alloc((size_t)E * 4);
    float* dinv     = (float*)alloc((size_t)N * 4);
    f16*   h1       = (f16*)alloc((size_t)N * HID * 2);
    float* x1       = (float*)alloc((size_t)N * HID * 4);
    f16*   hg       = (f16*)alloc((size_t)N * HF * 2);
    float* a_s      = (float*)alloc((size_t)N * HEADS * 4);
    float* a_d      = (float*)alloc((size_t)N * HEADS * 4);
    f16*   h2       = (f16*)alloc((size_t)N * HID * 2);
    float* x3       = (float*)alloc((size_t)N * HID * 4);
    f16*   h3       = (f16*)alloc((size_t)N * HID * 2);
    float* x4       = (float*)alloc((size_t)N * HID * 4);
    if (off > ws_size) return;

    hipMemsetAsync(count, 0, zbytes, stream);    // zeros count+cursor+red+done

    int eb = (E + 255) / 256;
    int nb16 = (N + 15) / 16;
    int nbw  = (N + 3) / 4;      // one wave per node, 256-thread blocks

    k_detect<<<1, 256, 0, stream>>>((const int*)ei, E, flag);
    k_convert<<<eb, 256, 0, stream>>>(ei, E, flag, src32, dst32, count);
    k_scan<<<1, 1024, 0, stream>>>(count, rowstart, dinv, N);
    k_fill<<<eb, 256, 0, stream>>>(src32, dst32, E, rowstart, cursor, csr);

    k_gemm1<<<nb16, 256, 0, stream>>>(x, W1, h1, N);
    k_gcn_agg<<<nbw, 256, 0, stream>>>(h1, rowstart, csr, dinv, b1, nullptr, x1, N);

    k_gemm_gat<<<2048, 192, 0, stream>>>(x1, Wg, att_s, att_d, hg, a_s, a_d, N);
    k_gat_agg<<<nbw, 256, 0, stream>>>(hg, a_s, a_d, rowstart, csr, bg, W2, h2, N);

    k_gcn_agg_f3<<<nbw, 256, 0, stream>>>(h2, rowstart, csr, dinv, b2, W3, x3, h3, N);
    k_gcn_agg<<<nbw, 256, 0, stream>>>(h3, rowstart, csr, dinv, b3, x3, x4, N);

    k_mean_final<<<128, 256, 0, stream>>>(x4, red, done, Wlin, blin, out,
                                          1.0f / (float)N, N, 128);
}